// Round 2
// baseline (435.940 us; speedup 1.0000x reference)
//
#include <hip/hip_runtime.h>
#include <stdint.h>

#define K_TOT 4096
#define N_TOT 11008
#define M_TOT 256
#define BM 128
#define BN 64
#define WST 72   // padded LDS row stride in ushorts (144B = 16B-aligned, 2-way-free banks)

using bf16x8 = __attribute__((ext_vector_type(8))) short;
using f32x4  = __attribute__((ext_vector_type(4))) float;

// lgkmcnt-only barrier: LDS visibility without draining the vmem (W-prefetch) queue.
// __syncthreads() would emit s_waitcnt vmcnt(0) and kill the global prefetch pipeline.
#define BAR() do {                                          \
    asm volatile("s_waitcnt lgkmcnt(0)" ::: "memory");      \
    __builtin_amdgcn_s_barrier();                           \
    asm volatile("" ::: "memory");                          \
} while (0)

// ---------- prep: fp32 -> bf16 (RNE) for the activation ----------
__global__ void cvt_a_bf16(const float* __restrict__ in, uint32_t* __restrict__ out) {
    int i = blockIdx.x * blockDim.x + threadIdx.x;       // one float4 per thread
    const float4 v = ((const float4*)in)[i];
    uint32_t a = __float_as_uint(v.x), b = __float_as_uint(v.y),
             c = __float_as_uint(v.z), d = __float_as_uint(v.w);
    a += 0x7FFFu + ((a >> 16) & 1u);
    b += 0x7FFFu + ((b >> 16) & 1u);
    c += 0x7FFFu + ((c >> 16) & 1u);
    d += 0x7FFFu + ((d >> 16) & 1u);
    uint2 o;
    o.x = (a >> 16) | (b & 0xFFFF0000u);
    o.y = (c >> 16) | (d & 0xFFFF0000u);
    ((uint2*)out)[i] = o;
}

__device__ __forceinline__ uint32_t pack_hi16(uint32_t u0, uint32_t u1) {
#if __has_builtin(__builtin_amdgcn_perm)
    return __builtin_amdgcn_perm(u1, u0, 0x07060302u);   // bytes {u0.b2,u0.b3,u1.b2,u1.b3}
#else
    return (u0 >> 16) | (u1 & 0xFFFF0000u);
#endif
}

__device__ __forceinline__ float clamp3(float q, float lo, float hi) {
#if __has_builtin(__builtin_amdgcn_fmed3f)
    return __builtin_amdgcn_fmed3f(q, lo, hi);           // lo<=hi always (0<=zp<=15)
#else
    return fminf(fmaxf(q, lo), hi);
#endif
}

// ---------- dequant 16 fp32 -> 16 bf16 packed into 8 dwords ----------
// clamp(round(w*rs)+zp,0,15)-zp  ==  med3(rint(w*rs), -zp, 15-zp)   (exact: small ints in fp32)
__device__ __forceinline__ void dequant16(const f32x4* w, float rs, float lo, float hi,
                                          float sc, uint32_t o[8]) {
    uint32_t u[16];
#pragma unroll
    for (int j = 0; j < 4; ++j) {
#pragma unroll
        for (int e = 0; e < 4; ++e) {
            float q  = rintf(w[j][e] * rs);              // round-half-even, matches jnp.round
            q        = clamp3(q, lo, hi);
            float dq = q * sc;
            uint32_t b = __float_as_uint(dq);
            u[4 * j + e] = b + 0x7FFFu + ((b >> 16) & 1u);   // bf16 RNE in high 16 bits
        }
    }
#pragma unroll
    for (int i = 0; i < 8; ++i) o[i] = pack_hi16(u[2 * i], u[2 * i + 1]);
}

// ---------- fused dequant + GEMM over a K-chunk, writes fp32 partials ----------
// vmem issue discipline (vmcnt is FIFO — a wait retires everything older):
//   iter u:  [issue A(u+1) regs] | [issue W(u+3) bank] | [compute(u): waits A(u) only,
//            leaves W(u+2),W(u+3) in flight] | [dequant(u+1): its W is already retired]
// sched_barrier(0) fences pin this order against scheduler load-clustering.
__global__ __launch_bounds__(256, 3)
void wql_gemm(const uint16_t* __restrict__ A,      // bf16 [256][4096]
              const float* __restrict__ W,         // fp32 [11008][4096]
              const float* __restrict__ scale,
              const float* __restrict__ zero,
              float* __restrict__ P,               // fp32 [KS][256][11008]
              int kloc) {                          // K-chunk length (multiple of 256)
    __shared__ uint16_t sW[2][BN][WST];            // 18.4 KB, double-buffered W tile (bf16)

    const int tid  = threadIdx.x;
    const int lane = tid & 63;
    const int wv   = tid >> 6;
    const int wm   = (wv & 1) * 64;
    const int wn   = (wv >> 1) * 32;
    const int m0   = blockIdx.x * BM;
    const int n0   = blockIdx.y * BN;
    const int k0   = blockIdx.z * kloc;
    const int nkt  = kloc >> 6;                    // 64-K steps (multiple of 4)

    // --- W staging role: thread owns one (row, 16-float k-segment) slot ---
    const int nloc = tid >> 2;                     // 0..63
    const int kseg = tid & 3;                      // 0..3
    const int wrow = n0 + nloc;
    const float* Wp = W + (size_t)wrow * K_TOT + k0 + kseg * 16;
    const float sc = scale[wrow];
    const float zp = zero[wrow];
    const float rs = 1.0f / sc;
    const float lo = -zp, hi = 15.0f - zp;

    // --- A fragment base pointers (direct-from-global, L2/LLC-resident) ---
    const uint16_t* Ap[4];
#pragma unroll
    for (int mi = 0; mi < 4; ++mi)
        Ap[mi] = A + (size_t)(m0 + wm + mi * 16 + (lane & 15)) * K_TOT + k0 + (lane >> 4) * 8;

    f32x4 acc[4][2];
#pragma unroll
    for (int mi = 0; mi < 4; ++mi)
#pragma unroll
        for (int ni = 0; ni < 2; ++ni)
            acc[mi][ni] = (f32x4){0.f, 0.f, 0.f, 0.f};

    f32x4  bank[4][4];     // W register banks; bank[(step)&3] holds W-block `step`
    bf16x8 ar[2][4][2];    // A fragments, double-buffered one step ahead

    // ---- prologue ----
    {   // W(0) -> bank[0]; dequant -> sW[0]
        const f32x4* p = (const f32x4*)Wp;
#pragma unroll
        for (int j = 0; j < 4; ++j) bank[0][j] = p[j];
        uint32_t o[8];
        dequant16(bank[0], rs, lo, hi, sc, o);
        uint16_t* d = &sW[0][nloc][kseg * 16];
        ((uint4*)d)[0] = make_uint4(o[0], o[1], o[2], o[3]);
        ((uint4*)d)[1] = make_uint4(o[4], o[5], o[6], o[7]);
    }
    // A(0) -> ar[0]  (issued BEFORE W(1),W(2) so compute(0)'s wait leaves them in flight)
#pragma unroll
    for (int mi = 0; mi < 4; ++mi)
#pragma unroll
        for (int s = 0; s < 2; ++s)
            ar[0][mi][s] = *(const bf16x8*)(Ap[mi] + s * 32);
    __builtin_amdgcn_sched_barrier(0);
    // W(1) -> bank[1]; W(2) -> bank[2]
#pragma unroll
    for (int ps = 1; ps <= 2; ++ps) {
        const f32x4* p = (const f32x4*)(Wp + (size_t)ps * 64);
#pragma unroll
        for (int j = 0; j < 4; ++j) bank[ps][j] = p[j];
    }
    BAR();

    for (int st = 0; st < nkt; st += 4) {
#pragma unroll
        for (int u = 0; u < 4; ++u) {              // all bank/sW/ar indices compile-time
            const int step = st + u;

            // pos1: A prefetch for step+1 (oldest issue this iter)
            if (step + 1 < nkt) {
                const int koff = (step + 1) * 64;
#pragma unroll
                for (int mi = 0; mi < 4; ++mi)
#pragma unroll
                    for (int s = 0; s < 2; ++s)
                        ar[(u + 1) & 1][mi][s] = *(const bf16x8*)(Ap[mi] + koff + s * 32);
            }
            __builtin_amdgcn_sched_barrier(0);

            // pos2: W prefetch for step+3
            if (step + 3 < nkt) {
                const f32x4* p = (const f32x4*)(Wp + (size_t)(step + 3) * 64);
#pragma unroll
                for (int j = 0; j < 4; ++j) bank[(u + 3) & 3][j] = p[j];
            }
            __builtin_amdgcn_sched_barrier(0);

            // pos3: compute step from ar[u&1] (regs) + sW[u&1] (LDS)
            {
#pragma unroll
                for (int s = 0; s < 2; ++s) {
                    bf16x8 b[2];
#pragma unroll
                    for (int ni = 0; ni < 2; ++ni)
                        b[ni] = *(const bf16x8*)&sW[u & 1][wn + ni * 16 + (lane & 15)]
                                                  [s * 32 + (lane >> 4) * 8];
#pragma unroll
                    for (int mi = 0; mi < 4; ++mi)
#pragma unroll
                        for (int ni = 0; ni < 2; ++ni)
                            acc[mi][ni] = __builtin_amdgcn_mfma_f32_16x16x32_bf16(
                                ar[u & 1][mi][s], b[ni], acc[mi][ni], 0, 0, 0);
                }
            }

            // pos4: dequant step+1 into the other LDS half (its W bank is already retired)
            if (step + 1 < nkt) {
                uint32_t o[8];
                dequant16(bank[(u + 1) & 3], rs, lo, hi, sc, o);
                uint16_t* d = &sW[(u + 1) & 1][nloc][kseg * 16];
                ((uint4*)d)[0] = make_uint4(o[0], o[1], o[2], o[3]);
                ((uint4*)d)[1] = make_uint4(o[4], o[5], o[6], o[7]);
            }

            BAR();
        }
    }

    // --- epilogue: store fp32 partial (no bias here) ---
    float* Pb = P + (size_t)blockIdx.z * M_TOT * N_TOT;
    const int colbase = n0 + wn + (lane & 15);
    const int rbase = m0 + wm + ((lane >> 4) << 2);
#pragma unroll
    for (int mi = 0; mi < 4; ++mi) {
#pragma unroll
        for (int ni = 0; ni < 2; ++ni) {
            const int col = colbase + ni * 16;
#pragma unroll
            for (int r = 0; r < 4; ++r) {
                const int row = rbase + mi * 16 + r;
                Pb[(size_t)row * N_TOT + col] = acc[mi][ni][r];
            }
        }
    }
}

// ---------- reduce KS partial slices + bias -> out (float4 per thread) ----------
__global__ void reduce_bias(const float* __restrict__ P, const float* __restrict__ bias,
                            float* __restrict__ out, int ks) {
    const int i4 = blockIdx.x * blockDim.x + threadIdx.x;   // float4 index
    const size_t tot4 = (size_t)M_TOT * N_TOT / 4;
    const int col = (int)(((size_t)i4 * 4) % N_TOT);        // rows are multiple-of-4 long
    float4 acc = ((const float4*)P)[i4];
    for (int s = 1; s < ks; ++s) {
        const float4 v = ((const float4*)P)[(size_t)s * tot4 + i4];
        acc.x += v.x; acc.y += v.y; acc.z += v.z; acc.w += v.w;
    }
    const float4 b = *(const float4*)(bias + col);
    acc.x += b.x; acc.y += b.y; acc.z += b.z; acc.w += b.w;
    ((float4*)out)[i4] = acc;
}

extern "C" void kernel_launch(void* const* d_in, const int* in_sizes, int n_in,
                              void* d_out, int out_size, void* d_ws, size_t ws_size,
                              hipStream_t stream) {
    const float* inp    = (const float*)d_in[0];
    const float* weight = (const float*)d_in[1];
    const float* bias   = (const float*)d_in[2];
    const float* scale  = (const float*)d_in[3];
    const float* zero   = (const float*)d_in[4];
    // d_in[5] = maxq scalar; fixed at 15 by the reference, hardcoded in dequant16.

    const size_t A_BYTES = (size_t)M_TOT * K_TOT * 2;       // 2 MB bf16 activation
    const size_t SLICE   = (size_t)M_TOT * N_TOT * 4;       // 11 MB fp32 partial

    uint32_t* Abf = (uint32_t*)d_ws;
    float* partial;
    int KS;
    if (ws_size >= A_BYTES + 4 * SLICE) { KS = 4; partial = (float*)((char*)d_ws + A_BYTES); }
    else if (ws_size >= A_BYTES + 2 * SLICE) { KS = 2; partial = (float*)((char*)d_ws + A_BYTES); }
    else { KS = 1; partial = (float*)d_out; }               // in-place: reduce adds bias only

    cvt_a_bf16<<<dim3((M_TOT * K_TOT / 4) / 256), dim3(256), 0, stream>>>(inp, Abf);

    dim3 grid(M_TOT / BM, N_TOT / BN, KS);                  // (2, 172, KS)
    wql_gemm<<<grid, dim3(256), 0, stream>>>((const uint16_t*)Abf, weight, scale, zero,
                                             partial, K_TOT / KS);

    reduce_bias<<<dim3((M_TOT * N_TOT / 4) / 256), dim3(256), 0, stream>>>(
        partial, bias, (float*)d_out, KS);
}

// Round 3
// 340.361 us; speedup vs baseline: 1.2808x; 1.2808x over previous
//
#include <hip/hip_runtime.h>
#include <stdint.h>

#define K_TOT 4096
#define N_TOT 11008
#define M_TOT 256
#define BM 128
#define BN 64
#define WST 72   // padded LDS row stride in ushorts (144B = 16B-aligned, 2-way-free banks)

using bf16x8 = __attribute__((ext_vector_type(8))) short;
using f32x4  = __attribute__((ext_vector_type(4))) float;

// lgkmcnt-only barrier: LDS visibility without draining the vmem (W-prefetch) queue.
// __syncthreads() would emit s_waitcnt vmcnt(0) and kill the global prefetch pipeline.
#define BAR() do {                                          \
    asm volatile("s_waitcnt lgkmcnt(0)" ::: "memory");      \
    __builtin_amdgcn_s_barrier();                           \
    asm volatile("" ::: "memory");                          \
} while (0)

#define MFMA(A, B, C) __builtin_amdgcn_mfma_f32_16x16x32_bf16((A), (B), (C), 0, 0, 0)

// ---------- prep: fp32 -> bf16 (RNE) for the activation ----------
__global__ void cvt_a_bf16(const float* __restrict__ in, uint32_t* __restrict__ out) {
    int i = blockIdx.x * blockDim.x + threadIdx.x;       // one float4 per thread
    const float4 v = ((const float4*)in)[i];
    uint32_t a = __float_as_uint(v.x), b = __float_as_uint(v.y),
             c = __float_as_uint(v.z), d = __float_as_uint(v.w);
    a += 0x7FFFu + ((a >> 16) & 1u);
    b += 0x7FFFu + ((b >> 16) & 1u);
    c += 0x7FFFu + ((c >> 16) & 1u);
    d += 0x7FFFu + ((d >> 16) & 1u);
    uint2 o;
    o.x = (a >> 16) | (b & 0xFFFF0000u);
    o.y = (c >> 16) | (d & 0xFFFF0000u);
    ((uint2*)out)[i] = o;
}

__device__ __forceinline__ uint32_t pack_hi16(uint32_t u0, uint32_t u1) {
#if __has_builtin(__builtin_amdgcn_perm)
    return __builtin_amdgcn_perm(u1, u0, 0x07060302u);   // bytes {u0.b2,u0.b3,u1.b2,u1.b3}
#else
    return (u0 >> 16) | (u1 & 0xFFFF0000u);
#endif
}

__device__ __forceinline__ float clamp3(float q, float lo, float hi) {
#if __has_builtin(__builtin_amdgcn_fmed3f)
    return __builtin_amdgcn_fmed3f(q, lo, hi);           // lo<=hi always (0<=zp<=15)
#else
    return fminf(fmaxf(q, lo), hi);
#endif
}

// ---------- dequant 16 fp32 -> 16 bf16 packed into 8 dwords ----------
// clamp(round(w*rs)+zp,0,15)-zp  ==  med3(rint(w*rs), -zp, 15-zp)   (exact: small ints in fp32)
__device__ __forceinline__ void dequant16(const f32x4* w, float rs, float lo, float hi,
                                          float sc, uint32_t o[8]) {
    uint32_t u[16];
#pragma unroll
    for (int j = 0; j < 4; ++j) {
#pragma unroll
        for (int e = 0; e < 4; ++e) {
            float q  = rintf(w[j][e] * rs);              // round-half-even, matches jnp.round
            q        = clamp3(q, lo, hi);
            float dq = q * sc;
            uint32_t b = __float_as_uint(dq);
            u[4 * j + e] = b + 0x7FFFu + ((b >> 16) & 1u);   // bf16 RNE in high 16 bits
        }
    }
#pragma unroll
    for (int i = 0; i < 8; ++i) o[i] = pack_hi16(u[2 * i], u[2 * i + 1]);
}

// One 64-K step. vmem issue order (vmcnt FIFO: a wait retires everything older):
//   [A(s): 8 loads, issued first] [W(s+2): 4 loads] | compute waits A(s) -> retires
//   W(s+1) (needed by dequant now anyway) but leaves W(s+2) in flight | dequant W(s+1).
// All buffer names/parities are literal: nothing here can fall to scratch (rule #20).
#define ITER(STEP, CUR, NXT, P) do {                                            \
    const int _s = (STEP);                                                      \
    const int _koff = _s * 64;                                                  \
    /* pos1: A fragment loads for this step (oldest vmem this iter) */          \
    bf16x8 a0 = *(const bf16x8*)(Ap0 + _koff),                                  \
           a1 = *(const bf16x8*)(Ap0 + _koff + 32),                             \
           a2 = *(const bf16x8*)(Ap1 + _koff),                                  \
           a3 = *(const bf16x8*)(Ap1 + _koff + 32),                             \
           a4 = *(const bf16x8*)(Ap2 + _koff),                                  \
           a5 = *(const bf16x8*)(Ap2 + _koff + 32),                             \
           a6 = *(const bf16x8*)(Ap3 + _koff),                                  \
           a7 = *(const bf16x8*)(Ap3 + _koff + 32);                             \
    __builtin_amdgcn_sched_barrier(0);                                          \
    /* pos2: W prefetch (s+2) into CUR; newest vmem -> survives compute wait */ \
    if (_s + 2 < nkt) {                                                         \
        const f32x4* _p = (const f32x4*)(Wp + (size_t)(_s + 2) * 64);           \
        CUR[0] = _p[0]; CUR[1] = _p[1]; CUR[2] = _p[2]; CUR[3] = _p[3];         \
    }                                                                           \
    __builtin_amdgcn_sched_barrier(0);                                          \
    /* pos3: compute step from sW[P] + a regs */                                \
    {                                                                           \
        bf16x8 b00 = *(const bf16x8*)&sW[P][wn +      (lane & 15)][(lane >> 4) * 8]; \
        bf16x8 b01 = *(const bf16x8*)&sW[P][wn + 16 + (lane & 15)][(lane >> 4) * 8]; \
        acc[0][0] = MFMA(a0, b00, acc[0][0]);                                   \
        acc[0][1] = MFMA(a0, b01, acc[0][1]);                                   \
        acc[1][0] = MFMA(a2, b00, acc[1][0]);                                   \
        acc[1][1] = MFMA(a2, b01, acc[1][1]);                                   \
        acc[2][0] = MFMA(a4, b00, acc[2][0]);                                   \
        acc[2][1] = MFMA(a4, b01, acc[2][1]);                                   \
        acc[3][0] = MFMA(a6, b00, acc[3][0]);                                   \
        acc[3][1] = MFMA(a6, b01, acc[3][1]);                                   \
        bf16x8 b10 = *(const bf16x8*)&sW[P][wn +      (lane & 15)][32 + (lane >> 4) * 8]; \
        bf16x8 b11 = *(const bf16x8*)&sW[P][wn + 16 + (lane & 15)][32 + (lane >> 4) * 8]; \
        acc[0][0] = MFMA(a1, b10, acc[0][0]);                                   \
        acc[0][1] = MFMA(a1, b11, acc[0][1]);                                   \
        acc[1][0] = MFMA(a3, b10, acc[1][0]);                                   \
        acc[1][1] = MFMA(a3, b11, acc[1][1]);                                   \
        acc[2][0] = MFMA(a5, b10, acc[2][0]);                                   \
        acc[2][1] = MFMA(a5, b11, acc[2][1]);                                   \
        acc[3][0] = MFMA(a7, b10, acc[3][0]);                                   \
        acc[3][1] = MFMA(a7, b11, acc[3][1]);                                   \
    }                                                                           \
    /* pos4: dequant W(s+1) from NXT into the other LDS half */                 \
    if (_s + 1 < nkt) {                                                         \
        uint32_t o[8];                                                          \
        dequant16(NXT, rs, lo, hi, sc, o);                                      \
        uint16_t* _d = &sW[P ^ 1][nloc][kseg * 16];                             \
        ((uint4*)_d)[0] = make_uint4(o[0], o[1], o[2], o[3]);                   \
        ((uint4*)_d)[1] = make_uint4(o[4], o[5], o[6], o[7]);                   \
    }                                                                           \
    BAR();                                                                      \
} while (0)

// ---------- fused dequant + GEMM over a K-chunk, writes fp32 partials ----------
__global__ __launch_bounds__(256, 3)
void wql_gemm(const uint16_t* __restrict__ A,      // bf16 [256][4096]
              const float* __restrict__ W,         // fp32 [11008][4096]
              const float* __restrict__ scale,
              const float* __restrict__ zero,
              float* __restrict__ P,               // fp32 [KS][256][11008]
              int kloc) {                          // K-chunk length (multiple of 128)
    __shared__ uint16_t sW[2][BN][WST];            // 18.4 KB, double-buffered W tile (bf16)

    const int tid  = threadIdx.x;
    const int lane = tid & 63;
    const int wv   = tid >> 6;
    const int wm   = (wv & 1) * 64;
    const int wn   = (wv >> 1) * 32;
    const int m0   = blockIdx.x * BM;
    const int n0   = blockIdx.y * BN;
    const int k0   = blockIdx.z * kloc;
    const int nkt  = kloc >> 6;                    // 64-K steps (even)

    // --- W staging role: thread owns one (row, 16-float k-segment) slot ---
    const int nloc = tid >> 2;                     // 0..63
    const int kseg = tid & 3;                      // 0..3
    const int wrow = n0 + nloc;
    const float* Wp = W + (size_t)wrow * K_TOT + k0 + kseg * 16;
    const float sc = scale[wrow];
    const float zp = zero[wrow];
    const float rs = 1.0f / sc;
    const float lo = -zp, hi = 15.0f - zp;

    // --- A fragment base pointers (direct-from-global, L2/LLC-resident) ---
    const uint16_t* Ap0 = A + (size_t)(m0 + wm +  0 + (lane & 15)) * K_TOT + k0 + (lane >> 4) * 8;
    const uint16_t* Ap1 = A + (size_t)(m0 + wm + 16 + (lane & 15)) * K_TOT + k0 + (lane >> 4) * 8;
    const uint16_t* Ap2 = A + (size_t)(m0 + wm + 32 + (lane & 15)) * K_TOT + k0 + (lane >> 4) * 8;
    const uint16_t* Ap3 = A + (size_t)(m0 + wm + 48 + (lane & 15)) * K_TOT + k0 + (lane >> 4) * 8;

    f32x4 acc[4][2];
#pragma unroll
    for (int mi = 0; mi < 4; ++mi)
#pragma unroll
        for (int ni = 0; ni < 2; ++ni)
            acc[mi][ni] = (f32x4){0.f, 0.f, 0.f, 0.f};

    f32x4 bank0[4], bank1[4];   // two raw-W register banks, statically named

    // ---- prologue: issue W(0), W(1); dequant W(0)->sW[0] (leaves W(1) in flight) ----
    {
        const f32x4* p0 = (const f32x4*)Wp;
        bank0[0] = p0[0]; bank0[1] = p0[1]; bank0[2] = p0[2]; bank0[3] = p0[3];
        const f32x4* p1 = (const f32x4*)(Wp + 64);
        bank1[0] = p1[0]; bank1[1] = p1[1]; bank1[2] = p1[2]; bank1[3] = p1[3];
    }
    __builtin_amdgcn_sched_barrier(0);
    {
        uint32_t o[8];
        dequant16(bank0, rs, lo, hi, sc, o);
        uint16_t* d = &sW[0][nloc][kseg * 16];
        ((uint4*)d)[0] = make_uint4(o[0], o[1], o[2], o[3]);
        ((uint4*)d)[1] = make_uint4(o[4], o[5], o[6], o[7]);
    }
    BAR();

    // ---- main loop: parity explicit; all indices literal ----
    for (int s = 0; s < nkt; s += 2) {
        ITER(s,     bank0, bank1, 0);   // compute sW[0]; dequant bank1=W(s+1)->sW[1]; load W(s+2)->bank0
        ITER(s + 1, bank1, bank0, 1);   // compute sW[1]; dequant bank0=W(s+2)->sW[0]; load W(s+3)->bank1
    }

    // --- epilogue: store fp32 partial (no bias here) ---
    float* Pb = P + (size_t)blockIdx.z * M_TOT * N_TOT;
    const int colbase = n0 + wn + (lane & 15);
    const int rbase = m0 + wm + ((lane >> 4) << 2);
#pragma unroll
    for (int mi = 0; mi < 4; ++mi) {
#pragma unroll
        for (int ni = 0; ni < 2; ++ni) {
            const int col = colbase + ni * 16;
#pragma unroll
            for (int r = 0; r < 4; ++r) {
                const int row = rbase + mi * 16 + r;
                Pb[(size_t)row * N_TOT + col] = acc[mi][ni][r];
            }
        }
    }
}

// ---------- reduce KS partial slices + bias -> out (float4 per thread) ----------
__global__ void reduce_bias(const float* __restrict__ P, const float* __restrict__ bias,
                            float* __restrict__ out, int ks) {
    const int i4 = blockIdx.x * blockDim.x + threadIdx.x;   // float4 index
    const size_t tot4 = (size_t)M_TOT * N_TOT / 4;
    const int col = (int)(((size_t)i4 * 4) % N_TOT);        // rows are multiple-of-4 long
    float4 acc = ((const float4*)P)[i4];
    for (int s = 1; s < ks; ++s) {
        const float4 v = ((const float4*)P)[(size_t)s * tot4 + i4];
        acc.x += v.x; acc.y += v.y; acc.z += v.z; acc.w += v.w;
    }
    const float4 b = *(const float4*)(bias + col);
    acc.x += b.x; acc.y += b.y; acc.z += b.z; acc.w += b.w;
    ((float4*)out)[i4] = acc;
}

extern "C" void kernel_launch(void* const* d_in, const int* in_sizes, int n_in,
                              void* d_out, int out_size, void* d_ws, size_t ws_size,
                              hipStream_t stream) {
    const float* inp    = (const float*)d_in[0];
    const float* weight = (const float*)d_in[1];
    const float* bias   = (const float*)d_in[2];
    const float* scale  = (const float*)d_in[3];
    const float* zero   = (const float*)d_in[4];
    // d_in[5] = maxq scalar; fixed at 15 by the reference, hardcoded in dequant16.

    const size_t A_BYTES = (size_t)M_TOT * K_TOT * 2;       // 2 MB bf16 activation
    const size_t SLICE   = (size_t)M_TOT * N_TOT * 4;       // 11 MB fp32 partial

    uint32_t* Abf = (uint32_t*)d_ws;
    float* partial;
    int KS;
    if (ws_size >= A_BYTES + 4 * SLICE) { KS = 4; partial = (float*)((char*)d_ws + A_BYTES); }
    else if (ws_size >= A_BYTES + 2 * SLICE) { KS = 2; partial = (float*)((char*)d_ws + A_BYTES); }
    else { KS = 1; partial = (float*)d_out; }               // in-place: reduce adds bias only

    cvt_a_bf16<<<dim3((M_TOT * K_TOT / 4) / 256), dim3(256), 0, stream>>>(inp, Abf);

    dim3 grid(M_TOT / BM, N_TOT / BN, KS);                  // (2, 172, KS)
    wql_gemm<<<grid, dim3(256), 0, stream>>>((const uint16_t*)Abf, weight, scale, zero,
                                             partial, K_TOT / KS);

    reduce_bias<<<dim3((M_TOT * N_TOT / 4) / 256), dim3(256), 0, stream>>>(
        partial, bias, (float*)d_out, KS);
}